// Round 6
// baseline (362.538 us; speedup 1.0000x reference)
//
#include <hip/hip_runtime.h>

// ---------------------------------------------------------------------------
// SympleAgent Tree-LSTM on MI355X — R6: single fused sweep with last-arriver
// tail. precompute -> memset(cnt) -> sweep_kernel (grid 2048 = 128 batches x
// 16 subtrees of 64 L10-rows). Each block: L10 gather + L9/L8/L7 in LDS,
// stores its 8 L7 rows to global, then atomically arrives at cnt[batch];
// the 16th arriver runs that batch's L6..L0 + head in the same kernel.
// ---------------------------------------------------------------------------

typedef unsigned short u16;
typedef unsigned int   u32;
typedef __attribute__((ext_vector_type(8))) short  short8;   // 8 bf16
typedef __attribute__((ext_vector_type(4))) float  floatx4;  // MFMA C/D frag

__device__ __forceinline__ float fsig(float x) {
    return __fdividef(1.0f, 1.0f + __expf(-x));
}
__device__ __forceinline__ float ftanh(float x) {
    return 1.0f - __fdividef(2.0f, __expf(2.0f * x) + 1.0f);
}
__device__ __forceinline__ u16 f2bfa(float x) {  // round-to-nearest
    return (u16)((__float_as_uint(x) + 0x8000u) >> 16);
}
__device__ __forceinline__ float bflo(u32 cc) { return __uint_as_float(cc << 16); }
__device__ __forceinline__ float bfhi(u32 cc) { return __uint_as_float(cc & 0xFFFF0000u); }

#define HS 76   // h LDS row stride (u16): child-pair dword stride 76 % 32 = 12
                // -> ~2-way bank aliasing on ds_read_b128 (free per m136)

// ---------------- precompute: 32B records + swizzled bf16 U ----------------
// grid 128 (block per vocab id), block 320.
// Wrec [id][hh][8]f : {i,fa,fb,o,u,0,0,0} of Wx[id]+b
// Tarec[id][hh][8]f : {i,fa,fb,o,u,leaf_c,0,0} of leaf_h[id]@Ua ; Tbrec w/ Ub
// Uswz: B-frag order, elem ((kc*20+nt)*64+lane)*8+j =
//       U[kc*32+(lane>>4)*8+j][nt*16+(lane&15)], U = vstack(Ua,Ub) (128x320).
__global__ void precompute_kernel(
    const float* __restrict__ Wx, const float* __restrict__ b_tree,
    const float* __restrict__ Ua, const float* __restrict__ Ub,
    float* __restrict__ Wrec, float* __restrict__ Tarec, float* __restrict__ Tbrec,
    u16* __restrict__ Uswz)
{
    int v = blockIdx.x;
    int t = threadIdx.x;
    __shared__ float sz[320], sta[320], stb[320], sh[64], sc[64];
    float z = Wx[v * 320 + t] + b_tree[t];
    sz[t] = z;
    {   // Uswz: one element per thread (128*320 total)
        int f = v * 320 + t;
        int j = f & 7, lane = (f >> 3) & 63, tk = f >> 9;
        int nt = tk % 20, kc = tk / 20;
        int k = kc * 32 + (lane >> 4) * 8 + j;
        int nn = nt * 16 + (lane & 15);
        float uval = (k < 64) ? Ua[k * 320 + nn] : Ub[(k - 64) * 320 + nn];
        Uswz[f] = (u16)((__float_as_uint(uval) + 0x7FFFu +
                         ((__float_as_uint(uval) >> 16) & 1u)) >> 16);
    }
    __syncthreads();
    if (t < 64) {
        float c = fsig(sz[t]) * ftanh(sz[256 + t]);
        float h = fsig(sz[192 + t]) * ftanh(c);
        sc[t] = c; sh[t] = h;
    }
    __syncthreads();
    float ta = 0.f, tb = 0.f;
    #pragma unroll 8
    for (int k = 0; k < 64; ++k) {
        ta += sh[k] * Ua[k * 320 + t];
        tb += sh[k] * Ub[k * 320 + t];
    }
    sta[t] = ta; stb[t] = tb;
    __syncthreads();
    if (t < 64) {
        float* w  = Wrec  + (((size_t)v << 6) + t) * 8;
        float* pa = Tarec + (((size_t)v << 6) + t) * 8;
        float* pb = Tbrec + (((size_t)v << 6) + t) * 8;
        *(float4*)w        = make_float4(sz[t], sz[64 + t], sz[128 + t], sz[192 + t]);
        *(float4*)(w + 4)  = make_float4(sz[256 + t], 0.f, 0.f, 0.f);
        *(float4*)pa       = make_float4(sta[t], sta[64 + t], sta[128 + t], sta[192 + t]);
        *(float4*)(pa + 4) = make_float4(sta[256 + t], sc[t], 0.f, 0.f);
        *(float4*)pb       = make_float4(stb[t], stb[64 + t], stb[128 + t], stb[192 + t]);
        *(float4*)(pb + 4) = make_float4(stb[256 + t], sc[t], 0.f, 0.f);
    }
}

// ---------------- one level call: NT 16-row tiles, MFMA + gate epilogue ----
// Wave wv owns hidden cols [wv*16,wv*16+16) for all 5 gates; every wave
// processes every tile. GSRC=1 reads A/c from global (row stride 64 u16 /
// paired u32); else LDS (HS / paired u32).
// MODE 0: LDS dst; MODE 1: global dst (guarded by nvalid); MODE 2: hroot.
template<int NT, int MODE, int GSRC>
__device__ __forceinline__ void sweep_level(
    const u16* hsrc, const u32* csrc,
    u16* hdst, u16* cdst, u16* hg, u16* cg, float* hroot,
    const short8 Bfrag[4][5],
    const float* __restrict__ Wrec,
    const int* ids, int lbase, int node0g, int nvalid,
    int lane15, int quad, int wv)
{
    floatx4 acc[NT][5];
    #pragma unroll
    for (int mt = 0; mt < NT; ++mt)
        #pragma unroll
        for (int g = 0; g < 5; ++g) acc[mt][g] = (floatx4){0.f, 0.f, 0.f, 0.f};

    #pragma unroll
    for (int mt = 0; mt < NT; ++mt) {
        #pragma unroll
        for (int kc = 0; kc < 4; ++kc) {
            int child = 2 * (lbase + mt * 16 + lane15) + (kc >> 1);
            const u16* ap = GSRC ? (hsrc + child * 64 + (kc & 1) * 32 + quad * 8)
                                 : (hsrc + child * HS + (kc & 1) * 32 + quad * 8);
            short8 a = *(const short8*)ap;
            #pragma unroll
            for (int g = 0; g < 5; ++g)
                acc[mt][g] = __builtin_amdgcn_mfma_f32_16x16x32_bf16(
                    a, Bfrag[kc][g], acc[mt][g], 0, 0, 0);
        }
    }
    int hh = wv * 16 + lane15;
    #pragma unroll
    for (int mt = 0; mt < NT; ++mt) {
        #pragma unroll
        for (int r = 0; r < 4; ++r) {
            int lrow = lbase + mt * 16 + quad * 4 + r;
            int id = ids[lrow];
            const float* w = Wrec + (((size_t)id << 6) + hh) * 8;
            float4 wg = *(const float4*)w;
            float  wu = w[4];
            u32 cc = csrc[lrow * 64 + hh];   // children pair of parent lrow
            float zi  = acc[mt][0][r] + wg.x;
            float zfa = acc[mt][1][r] + wg.y;
            float zfb = acc[mt][2][r] + wg.z;
            float zo  = acc[mt][3][r] + wg.w;
            float zu  = acc[mt][4][r] + wu;
            float c = fsig(zi) * ftanh(zu) + fsig(zfa) * bflo(cc) + fsig(zfb) * bfhi(cc);
            float h = fsig(zo) * ftanh(c);
            if (MODE == 0) {
                hdst[lrow * HS + hh] = f2bfa(h);
                cdst[(lrow >> 1) * 128 + hh * 2 + (lrow & 1)] = f2bfa(c);
            }
            if (MODE == 1) {
                if (lrow < nvalid) {
                    int node = node0g + lrow;
                    hg[node * 64 + hh] = f2bfa(h);
                    cg[(node >> 1) * 128 + hh * 2 + (node & 1)] = f2bfa(c);
                }
            }
            if (MODE == 2) {
                if (lrow == 0) hroot[hh] = h;
            }
        }
    }
}

__device__ __forceinline__ void load_bfrags(short8 Bfrag[4][5],
                                            const u16* __restrict__ Uswz,
                                            int wv, int lane)
{
    #pragma unroll
    for (int kc = 0; kc < 4; ++kc)
        #pragma unroll
        for (int g = 0; g < 5; ++g) {
            int nt = g * 4 + wv;
            Bfrag[kc][g] = *(const short8*)(Uswz + ((kc * 20 + nt) * 64 + lane) * 8);
        }
}

// ---------------- fused sweep: phase 1 (L10..L7) + last-arriver tail -------
// grid 2048 = 128 batches x 16 subtrees (64 L10-rows each); block 256.
__global__ __launch_bounds__(256, 3) void sweep_kernel(
    const int* __restrict__ x_idx,
    const float* __restrict__ Wrec, const float* __restrict__ Tarec,
    const float* __restrict__ Tbrec, const u16* __restrict__ Uswz,
    u16* __restrict__ h7, u16* __restrict__ c7, int* __restrict__ cnt,
    const float* __restrict__ W1, const float* __restrict__ b1,
    const float* __restrict__ W2, const float* __restrict__ b2,
    const float* __restrict__ W_ih, const float* __restrict__ b_lstm,
    const float* __restrict__ actor_W, const float* __restrict__ actor_b,
    const float* __restrict__ vm, float* __restrict__ out)
{
    __shared__ u16 hA[64 * HS];      // 9728 B
    __shared__ u16 cA[32 * 128];     // 8192 B (paired bf16)
    __shared__ u16 hB[32 * HS];      // 4864 B
    __shared__ u16 cB[16 * 128];     // 4096 B
    __shared__ int sIds[256];
    __shared__ float hroot[64];
    __shared__ int go;
    int t = threadIdx.x, lane = t & 63, wv = t >> 6;
    int lane15 = lane & 15, quad = lane >> 4;
    int b = blockIdx.x >> 4, st = blockIdx.x & 15;
    const int* xb = x_idx + b * 4095;
    u16* h7b = h7 + (size_t)b * 8192;
    u16* c7b = c7 + (size_t)b * 8192;

    // ---- stage this subtree's ids (all coalesced)
    if      (t < 64)  sIds[t] = xb[1023 + st * 64 + t];
    else if (t < 192) sIds[t] = xb[2047 + st * 128 + (t - 64)];
    else if (t < 224) sIds[t] = xb[511 + st * 32 + (t - 192)];
    else if (t < 240) sIds[t] = xb[255 + st * 16 + (t - 224)];
    else if (t < 248) sIds[t] = xb[127 + st * 8 + (t - 240)];
    else              sIds[t] = 0;
    __syncthreads();

    // ---- L10: 16 rows per wave, lane = hidden col, ids from LDS
    #pragma unroll 4
    for (int rr = 0; rr < 16; ++rr) {
        int rl = wv * 16 + rr;
        int id  = sIds[rl];
        int ida = sIds[64 + 2 * rl];
        int idb = sIds[65 + 2 * rl];
        const float* w  = Wrec  + (((size_t)id  << 6) + lane) * 8;
        const float* pa = Tarec + (((size_t)ida << 6) + lane) * 8;
        const float* pb = Tbrec + (((size_t)idb << 6) + lane) * 8;
        float4 wg = *(const float4*)w;   float  wu = w[4];
        float4 ga = *(const float4*)pa;  float2 ua = *(const float2*)(pa + 4);
        float4 gb = *(const float4*)pb;  float2 ub = *(const float2*)(pb + 4);
        float zi  = wg.x + ga.x + gb.x;
        float zfa = wg.y + ga.y + gb.y;
        float zfb = wg.z + ga.z + gb.z;
        float zo  = wg.w + ga.w + gb.w;
        float zu  = wu   + ua.x + ub.x;
        float c = fsig(zi) * ftanh(zu) + fsig(zfa) * ua.y + fsig(zfb) * ub.y;
        float h = fsig(zo) * ftanh(c);
        hA[rl * HS + lane] = f2bfa(h);
        cA[(rl >> 1) * 128 + lane * 2 + (rl & 1)] = f2bfa(c);
    }
    short8 Bfrag[4][5];
    load_bfrags(Bfrag, Uswz, wv, lane);
    __syncthreads();
    // ---- L9: 32 rows, src hA/cA -> hB/cB
    sweep_level<2, 0, 0>(hA, (const u32*)cA, hB, cB, nullptr, nullptr, nullptr,
                         Bfrag, Wrec, &sIds[192], 0, 0, 32, lane15, quad, wv);
    __syncthreads();
    // ---- L8: 16 rows, src hB/cB -> hA/cA
    sweep_level<1, 0, 0>(hB, (const u32*)cB, hA, cA, nullptr, nullptr, nullptr,
                         Bfrag, Wrec, &sIds[224], 0, 0, 16, lane15, quad, wv);
    __syncthreads();
    // ---- L7: 8 valid rows, src hA/cA -> global slice [st*8, st*8+8)
    sweep_level<1, 1, 0>(hA, (const u32*)cA, nullptr, nullptr, h7b, c7b, nullptr,
                         Bfrag, Wrec, &sIds[240], 0, st * 8, 8, lane15, quad, wv);

    // ---- arrive; last of the batch's 16 blocks runs the tail
    __syncthreads();   // all waves' global stores drained (vmcnt) before arrive
    if (t == 0) {
        __threadfence();   // release: make h7/c7 visible device-wide
        int old = __hip_atomic_fetch_add(&cnt[b], 1, __ATOMIC_ACQ_REL,
                                         __HIP_MEMORY_SCOPE_AGENT);
        go = (old == 15);
        if (old == 15) __threadfence();   // acquire: invalidate stale caches
    }
    __syncthreads();
    if (!go) return;

    // =================== tail: L6..L0 + head for batch b ===================
    if (t < 127) sIds[t] = xb[t];   // ids for L6..L0: level L at &sIds[(1<<L)-1]
    __syncthreads();
    // L6: 64 rows from GLOBAL h7/c7 -> hA/cA
    sweep_level<2, 0, 1>(h7b, (const u32*)c7b, hA, cA, nullptr, nullptr, nullptr,
                         Bfrag, Wrec, &sIds[63], 0, 0, 64, lane15, quad, wv);
    sweep_level<2, 0, 1>(h7b, (const u32*)c7b, hA, cA, nullptr, nullptr, nullptr,
                         Bfrag, Wrec, &sIds[63], 32, 0, 64, lane15, quad, wv);
    __syncthreads();
    // L5: 32 rows hA -> hB
    sweep_level<2, 0, 0>(hA, (const u32*)cA, hB, cB, nullptr, nullptr, nullptr,
                         Bfrag, Wrec, &sIds[31], 0, 0, 32, lane15, quad, wv);
    __syncthreads();
    // L4: 16 rows hB -> hA
    sweep_level<1, 0, 0>(hB, (const u32*)cB, hA, cA, nullptr, nullptr, nullptr,
                         Bfrag, Wrec, &sIds[15], 0, 0, 16, lane15, quad, wv);
    __syncthreads();
    // L3: 8 valid hA -> hB (garbage rows bounded, stored in-bounds)
    sweep_level<1, 0, 0>(hA, (const u32*)cA, hB, cB, nullptr, nullptr, nullptr,
                         Bfrag, Wrec, &sIds[7], 0, 0, 8, lane15, quad, wv);
    __syncthreads();
    // L2: 4 valid hB -> hA
    sweep_level<1, 0, 0>(hB, (const u32*)cB, hA, cA, nullptr, nullptr, nullptr,
                         Bfrag, Wrec, &sIds[3], 0, 0, 4, lane15, quad, wv);
    __syncthreads();
    // L1: 2 valid hA -> hB
    sweep_level<1, 0, 0>(hA, (const u32*)cA, hB, cB, nullptr, nullptr, nullptr,
                         Bfrag, Wrec, &sIds[1], 0, 0, 2, lane15, quad, wv);
    __syncthreads();
    // L0 -> fp32 hroot
    sweep_level<1, 2, 0>(hB, (const u32*)cB, nullptr, nullptr, nullptr, nullptr,
                         hroot, Bfrag, Wrec, &sIds[0], 0, 0, 1, lane15, quad, wv);
    __syncthreads();

    // ---- head: wave 0 only
    if (wv == 0) {
        float a = b1[lane];
        #pragma unroll 8
        for (int k = 0; k < 64; ++k) a += hroot[k] * W1[k * 64 + lane];
        float r1 = fmaxf(a, 0.f);
        float f = b2[lane];
        #pragma unroll 8
        for (int k = 0; k < 64; ++k) f += __shfl(r1, k) * W2[k * 64 + lane];
        float gi = b_lstm[lane], gg = b_lstm[128 + lane], go2 = b_lstm[192 + lane];
        #pragma unroll 8
        for (int k = 0; k < 64; ++k) {
            float fk = __shfl(f, k);
            gi  += fk * W_ih[k * 256 + lane];
            gg  += fk * W_ih[k * 256 + 128 + lane];
            go2 += fk * W_ih[k * 256 + 192 + lane];
        }
        float cg = fsig(gi) * ftanh(gg);
        float hg = fsig(go2) * ftanh(cg);
        int tt = (lane < 20) ? lane : 19;
        float dot = 0.f;
        #pragma unroll 8
        for (int k = 0; k < 64; ++k) {
            float fk = __shfl(f, k), hk = __shfl(hg, k);
            dot += fk * actor_W[k * 20 + tt] + hk * actor_W[(64 + k) * 20 + tt];
        }
        float m = vm[tt];
        float lg = logf(m) + dot * m + actor_b[tt] * m;
        float mx = -1e30f;
        #pragma unroll
        for (int j = 0; j < 20; ++j) mx = fmaxf(mx, __shfl(lg, j));
        float s = 0.f;
        #pragma unroll
        for (int j = 0; j < 20; ++j) s += __expf((__shfl(lg, j) - mx) * (1.0f / 3.0f));
        if (lane < 20) out[b * 20 + lane] = __expf((lg - mx) * (1.0f / 3.0f)) / s;
    }
}

// ---------------------------------------------------------------------------
extern "C" void kernel_launch(void* const* d_in, const int* in_sizes, int n_in,
                              void* d_out, int out_size, void* d_ws, size_t ws_size,
                              hipStream_t stream)
{
    const int*   x_idx   = (const int*)d_in[0];
    const float* vm      = (const float*)d_in[1];
    const float* Wx      = (const float*)d_in[2];
    const float* Ua      = (const float*)d_in[3];
    const float* Ub      = (const float*)d_in[4];
    const float* b_tree  = (const float*)d_in[5];
    const float* W_ih    = (const float*)d_in[6];
    const float* b_lstm  = (const float*)d_in[8];
    const float* W1      = (const float*)d_in[9];
    const float* b1      = (const float*)d_in[10];
    const float* W2      = (const float*)d_in[11];
    const float* b2      = (const float*)d_in[12];
    const float* actor_W = (const float*)d_in[13];
    const float* actor_b = (const float*)d_in[14];
    float* out = (float*)d_out;

    char* ws = (char*)d_ws;
    float* Wrec  = (float*)ws;  ws += 128 * 64 * 8 * 4;   // 256 KB
    float* Tarec = (float*)ws;  ws += 128 * 64 * 8 * 4;
    float* Tbrec = (float*)ws;  ws += 128 * 64 * 8 * 4;
    u16*   h7    = (u16*)ws;    ws += 128 * 128 * 64 * 2; // 2 MB
    u16*   c7    = (u16*)ws;    ws += 128 * 128 * 64 * 2; // 2 MB
    u16*   Uswz  = (u16*)ws;    ws += 128 * 320 * 2;
    int*   cnt   = (int*)ws;    ws += 128 * 4;

    hipMemsetAsync(cnt, 0, 128 * 4, stream);
    precompute_kernel<<<128, 320, 0, stream>>>(Wx, b_tree, Ua, Ub,
                                               Wrec, Tarec, Tbrec, Uswz);
    sweep_kernel<<<2048, 256, 0, stream>>>(x_idx, Wrec, Tarec, Tbrec, Uswz,
                                           h7, c7, cnt,
                                           W1, b1, W2, b2, W_ih, b_lstm,
                                           actor_W, actor_b, vm, out);
}

// Round 7
// 254.272 us; speedup vs baseline: 1.4258x; 1.4258x over previous
//
#include <hip/hip_runtime.h>

// ---------------------------------------------------------------------------
// SympleAgent Tree-LSTM on MI355X — R7: fence-free 3-launch, high-occupancy
// subtree sweep. precompute -> sweepA (L10..L7, grid 2048 = 128 batches x 16
// subtrees of 64 L10-rows, 27.9 KB LDS ~5 blocks/CU) -> sweepB (L6..L0+head,
// grid 128, L7 state read straight from global). Combined-rcp gate math:
// 6 exp + 3 rcp per element (was 12 transcendentals).
// ---------------------------------------------------------------------------

typedef unsigned short u16;
typedef unsigned int   u32;
typedef __attribute__((ext_vector_type(8))) short  short8;   // 8 bf16
typedef __attribute__((ext_vector_type(4))) float  floatx4;  // MFMA C/D frag

__device__ __forceinline__ float frcp(float x) { return __fdividef(1.0f, x); }
__device__ __forceinline__ float fsig(float x) { return frcp(1.0f + __expf(-x)); }
__device__ __forceinline__ float ftanh(float x) {
    return 1.0f - 2.0f * frcp(__expf(2.0f * x) + 1.0f);
}
__device__ __forceinline__ u16 f2bfa(float x) {  // round-to-nearest
    return (u16)((__float_as_uint(x) + 0x8000u) >> 16);
}
__device__ __forceinline__ float bflo(u32 cc) { return __uint_as_float(cc << 16); }
__device__ __forceinline__ float bfhi(u32 cc) { return __uint_as_float(cc & 0xFFFF0000u); }

// Full LSTM gate evaluation with shared reciprocals: 6 exp + 3 rcp.
// sig(fa)ca+sig(fb)cb = (ca*pfb+cb*pfa)/(pfa*pfb);  sig(i)tanh(u) =
// (1-eu2)/((1+ei)(1+eu2));  h = (1-ec2)/((1+eo)(1+ec2)).  -40 clamps keep
// every overflow path at its correct limit (0 or +/-1 factors).
__device__ __forceinline__ void lstm_gates(
    float zi, float zfa, float zfb, float zo, float zu,
    float ca, float cb, float& c, float& h)
{
    zi  = fmaxf(zi, -40.f);  zfa = fmaxf(zfa, -40.f);
    zfb = fmaxf(zfb, -40.f); zo  = fmaxf(zo, -40.f);
    zu  = fmaxf(zu, -40.f);
    float ei  = __expf(-zi),  efa = __expf(-zfa);
    float efb = __expf(-zfb), eo  = __expf(-zo);
    float eu2 = __expf(-2.f * zu);
    float pfa = 1.f + efa, pfb = 1.f + efb;
    float cf = (ca * pfb + cb * pfa) * frcp(pfa * pfb);
    c = (1.f - eu2) * frcp((1.f + ei) * (1.f + eu2)) + cf;
    float cc = fmaxf(c, -40.f);
    float ec2 = __expf(-2.f * cc);
    h = (1.f - ec2) * frcp((1.f + eo) * (1.f + ec2));
}

#define HS 76   // h LDS row stride (u16): ~2-way bank aliasing only (free)

// ---------------- precompute: dense fp32 tables + swizzled bf16 U ----------
// grid 128 (block per vocab id), block 320.
// WpA [id][hh] float4 = (i,fa,fb,o) of Wx[id]+b; WpU float = u gate.
// TaA/TaUC: leaf_h[id]@Ua, UC=(u, leaf_c); TbA/TbUC with Ub.
// Uswz: B-frag order, elem ((kc*20+nt)*64+lane)*8+j =
//       U[kc*32+(lane>>4)*8+j][nt*16+(lane&15)], U = vstack(Ua,Ub) (128x320).
__global__ void precompute_kernel(
    const float* __restrict__ Wx, const float* __restrict__ b_tree,
    const float* __restrict__ Ua, const float* __restrict__ Ub,
    float4* __restrict__ WpA, float* __restrict__ WpU,
    float4* __restrict__ TaA, float2* __restrict__ TaUC,
    float4* __restrict__ TbA, float2* __restrict__ TbUC,
    u16* __restrict__ Uswz)
{
    int v = blockIdx.x;
    int t = threadIdx.x;
    __shared__ float sz[320], sta[320], stb[320], sh[64], sc[64];
    float z = Wx[v * 320 + t] + b_tree[t];
    sz[t] = z;
    {   // Uswz: one element per thread (128*320 total)
        int f = v * 320 + t;
        int j = f & 7, lane = (f >> 3) & 63, tk = f >> 9;
        int nt = tk % 20, kc = tk / 20;
        int k = kc * 32 + (lane >> 4) * 8 + j;
        int nn = nt * 16 + (lane & 15);
        float uval = (k < 64) ? Ua[k * 320 + nn] : Ub[(k - 64) * 320 + nn];
        Uswz[f] = (u16)((__float_as_uint(uval) + 0x7FFFu +
                         ((__float_as_uint(uval) >> 16) & 1u)) >> 16);
    }
    __syncthreads();
    if (t < 64) {
        float c = fsig(sz[t]) * ftanh(sz[256 + t]);
        float h = fsig(sz[192 + t]) * ftanh(c);
        sc[t] = c; sh[t] = h;
    }
    __syncthreads();
    float ta = 0.f, tb = 0.f;
    #pragma unroll 8
    for (int k = 0; k < 64; ++k) {
        ta += sh[k] * Ua[k * 320 + t];
        tb += sh[k] * Ub[k * 320 + t];
    }
    sta[t] = ta; stb[t] = tb;
    __syncthreads();
    if (t < 64) {
        int o = (v << 6) + t;
        WpA[o]  = make_float4(sz[t],  sz[64 + t],  sz[128 + t],  sz[192 + t]);
        WpU[o]  = sz[256 + t];
        TaA[o]  = make_float4(sta[t], sta[64 + t], sta[128 + t], sta[192 + t]);
        TaUC[o] = make_float2(sta[256 + t], sc[t]);
        TbA[o]  = make_float4(stb[t], stb[64 + t], stb[128 + t], stb[192 + t]);
        TbUC[o] = make_float2(stb[256 + t], sc[t]);
    }
}

// ---------------- one level call: NT 16-row tiles, MFMA + gate epilogue ----
// Wave wv owns hidden cols [wv*16,wv*16+16) for all 5 gates; every wave
// processes every tile. GSRC=1: A/c from global (h row stride 64 u16, c
// paired u32); GSRC=0: LDS (stride HS / paired u32).
// MODE 0: LDS dst; MODE 1: global dst (guarded by nvalid); MODE 2: hroot.
template<int NT, int MODE, int GSRC>
__device__ __forceinline__ void sweep_level(
    const u16* hsrc, const u32* csrc,
    u16* hdst, u16* cdst, u16* hg, u16* cg, float* hroot,
    const short8 Bfrag[4][5],
    const float4* __restrict__ WpA, const float* __restrict__ WpU,
    const int* ids, int lbase, int node0g, int nvalid,
    int lane15, int quad, int wv)
{
    floatx4 acc[NT][5];
    #pragma unroll
    for (int mt = 0; mt < NT; ++mt)
        #pragma unroll
        for (int g = 0; g < 5; ++g) acc[mt][g] = (floatx4){0.f, 0.f, 0.f, 0.f};

    #pragma unroll
    for (int mt = 0; mt < NT; ++mt) {
        #pragma unroll
        for (int kc = 0; kc < 4; ++kc) {
            int child = 2 * (lbase + mt * 16 + lane15) + (kc >> 1);
            const u16* ap = GSRC ? (hsrc + child * 64 + (kc & 1) * 32 + quad * 8)
                                 : (hsrc + child * HS + (kc & 1) * 32 + quad * 8);
            short8 a = *(const short8*)ap;
            #pragma unroll
            for (int g = 0; g < 5; ++g)
                acc[mt][g] = __builtin_amdgcn_mfma_f32_16x16x32_bf16(
                    a, Bfrag[kc][g], acc[mt][g], 0, 0, 0);
        }
    }
    int hh = wv * 16 + lane15;
    #pragma unroll
    for (int mt = 0; mt < NT; ++mt) {
        #pragma unroll
        for (int r = 0; r < 4; ++r) {
            int lrow = lbase + mt * 16 + quad * 4 + r;
            int id = ids[lrow];
            float4 wg = WpA[(id << 6) + hh];
            float  wu = WpU[(id << 6) + hh];
            u32 cc = csrc[lrow * 64 + hh];   // children c pair of parent lrow
            float c, h;
            lstm_gates(acc[mt][0][r] + wg.x, acc[mt][1][r] + wg.y,
                       acc[mt][2][r] + wg.z, acc[mt][3][r] + wg.w,
                       acc[mt][4][r] + wu, bflo(cc), bfhi(cc), c, h);
            if (MODE == 0) {
                hdst[lrow * HS + hh] = f2bfa(h);
                cdst[(lrow >> 1) * 128 + hh * 2 + (lrow & 1)] = f2bfa(c);
            }
            if (MODE == 1) {
                if (lrow < nvalid) {
                    int node = node0g + lrow;
                    hg[node * 64 + hh] = f2bfa(h);
                    cg[(node >> 1) * 128 + hh * 2 + (node & 1)] = f2bfa(c);
                }
            }
            if (MODE == 2) {
                if (lrow == 0) hroot[hh] = h;
            }
        }
    }
}

__device__ __forceinline__ void load_bfrags(short8 Bfrag[4][5],
                                            const u16* __restrict__ Uswz,
                                            int wv, int lane)
{
    #pragma unroll
    for (int kc = 0; kc < 4; ++kc)
        #pragma unroll
        for (int g = 0; g < 5; ++g) {
            int nt = g * 4 + wv;
            Bfrag[kc][g] = *(const short8*)(Uswz + ((kc * 20 + nt) * 64 + lane) * 8);
        }
}

// ---------------- phase A: L10..L7, grid 2048 = 128 x 16 subtrees ----------
// LDS: 9728 + 8192 + 4864 + 4096 + 1024 = 27904 B -> ~5 blocks/CU.
__global__ __launch_bounds__(256, 5) void sweepA_kernel(
    const int* __restrict__ x_idx,
    const float4* __restrict__ WpA, const float* __restrict__ WpU,
    const float4* __restrict__ TaA, const float2* __restrict__ TaUC,
    const float4* __restrict__ TbA, const float2* __restrict__ TbUC,
    const u16* __restrict__ Uswz,
    u16* __restrict__ h7, u16* __restrict__ c7)
{
    __shared__ u16 hA[64 * HS];
    __shared__ u16 cA[32 * 128];     // paired bf16: [pair][hh][parity]
    __shared__ u16 hB[32 * HS];
    __shared__ u16 cB[16 * 128];
    __shared__ int sIds[256];
    int t = threadIdx.x, lane = t & 63, wv = t >> 6;
    int lane15 = lane & 15, quad = lane >> 4;
    int b = blockIdx.x >> 4, st = blockIdx.x & 15;
    const int* xb = x_idx + b * 4095;
    u16* h7b = h7 + (size_t)b * 8192;
    u16* c7b = c7 + (size_t)b * 8192;

    // ---- stage this subtree's ids (coalesced)
    if      (t < 64)  sIds[t] = xb[1023 + st * 64 + t];           // L10
    else if (t < 192) sIds[t] = xb[2047 + st * 128 + (t - 64)];   // leaves
    else if (t < 224) sIds[t] = xb[511 + st * 32 + (t - 192)];    // L9
    else if (t < 240) sIds[t] = xb[255 + st * 16 + (t - 224)];    // L8
    else if (t < 248) sIds[t] = xb[127 + st * 8 + (t - 240)];     // L7
    else              sIds[t] = 0;
    __syncthreads();

    // ---- L10: 16 rows per wave, lane = hidden col, ids from LDS
    #pragma unroll 4
    for (int rr = 0; rr < 16; ++rr) {
        int rl = wv * 16 + rr;
        int id = sIds[rl], ida = sIds[64 + 2 * rl], idb = sIds[65 + 2 * rl];
        float4 wg = WpA[(id << 6) + lane];   float  wu = WpU[(id << 6) + lane];
        float4 ga = TaA[(ida << 6) + lane];  float2 ua = TaUC[(ida << 6) + lane];
        float4 gb = TbA[(idb << 6) + lane];  float2 ub = TbUC[(idb << 6) + lane];
        float c, h;
        lstm_gates(wg.x + ga.x + gb.x, wg.y + ga.y + gb.y, wg.z + ga.z + gb.z,
                   wg.w + ga.w + gb.w, wu + ua.x + ub.x, ua.y, ub.y, c, h);
        hA[rl * HS + lane] = f2bfa(h);
        cA[(rl >> 1) * 128 + lane * 2 + (rl & 1)] = f2bfa(c);
    }
    short8 Bfrag[4][5];
    load_bfrags(Bfrag, Uswz, wv, lane);
    __syncthreads();
    // ---- L9: 32 rows (2 tiles), hA/cA -> hB/cB
    sweep_level<2, 0, 0>(hA, (const u32*)cA, hB, cB, nullptr, nullptr, nullptr,
                         Bfrag, WpA, WpU, &sIds[192], 0, 0, 32, lane15, quad, wv);
    __syncthreads();
    // ---- L8: 16 rows (1 tile), hB/cB -> hA/cA
    sweep_level<1, 0, 0>(hB, (const u32*)cB, hA, cA, nullptr, nullptr, nullptr,
                         Bfrag, WpA, WpU, &sIds[224], 0, 0, 16, lane15, quad, wv);
    __syncthreads();
    // ---- L7: 8 valid rows of 1 tile, hA/cA -> global slice [st*8, st*8+8)
    sweep_level<1, 1, 0>(hA, (const u32*)cA, nullptr, nullptr, h7b, c7b, nullptr,
                         Bfrag, WpA, WpU, &sIds[240], 0, st * 8, 8, lane15, quad, wv);
}

// ---------------- phase B: L6..L0 + head, grid 128 -------------------------
__global__ __launch_bounds__(256, 2) void sweepB_kernel(
    const int* __restrict__ x_idx,
    const float4* __restrict__ WpA, const float* __restrict__ WpU,
    const u16* __restrict__ Uswz,
    const u16* __restrict__ h7, const u16* __restrict__ c7,
    const float* __restrict__ W1, const float* __restrict__ b1,
    const float* __restrict__ W2, const float* __restrict__ b2,
    const float* __restrict__ W_ih, const float* __restrict__ b_lstm,
    const float* __restrict__ actor_W, const float* __restrict__ actor_b,
    const float* __restrict__ vm, float* __restrict__ out)
{
    __shared__ u16 hA[64 * HS];
    __shared__ u16 cA[32 * 128];
    __shared__ u16 hB[32 * HS];
    __shared__ u16 cB[16 * 128];
    __shared__ int sIds[128];
    __shared__ float hroot[64];
    int t = threadIdx.x, lane = t & 63, wv = t >> 6;
    int lane15 = lane & 15, quad = lane >> 4;
    int b = blockIdx.x;
    const int* xb = x_idx + b * 4095;
    const u16* h7b = h7 + (size_t)b * 8192;
    const u16* c7b = c7 + (size_t)b * 8192;

    if (t < 127) sIds[t] = xb[t];   // level L's ids start at sIds[(1<<L)-1]
    short8 Bfrag[4][5];
    load_bfrags(Bfrag, Uswz, wv, lane);
    __syncthreads();
    // L6: 64 rows (2x NT=2 tiles) straight from global h7/c7 -> hA/cA
    sweep_level<2, 0, 1>(h7b, (const u32*)c7b, hA, cA, nullptr, nullptr, nullptr,
                         Bfrag, WpA, WpU, &sIds[63], 0, 0, 64, lane15, quad, wv);
    sweep_level<2, 0, 1>(h7b, (const u32*)c7b, hA, cA, nullptr, nullptr, nullptr,
                         Bfrag, WpA, WpU, &sIds[63], 32, 0, 64, lane15, quad, wv);
    __syncthreads();
    // L5: 32 rows, hA -> hB
    sweep_level<2, 0, 0>(hA, (const u32*)cA, hB, cB, nullptr, nullptr, nullptr,
                         Bfrag, WpA, WpU, &sIds[31], 0, 0, 32, lane15, quad, wv);
    __syncthreads();
    // L4: 16 rows, hB -> hA
    sweep_level<1, 0, 0>(hB, (const u32*)cB, hA, cA, nullptr, nullptr, nullptr,
                         Bfrag, WpA, WpU, &sIds[15], 0, 0, 16, lane15, quad, wv);
    __syncthreads();
    // L3: 8 valid, hA -> hB (garbage rows bounded, in-bounds)
    sweep_level<1, 0, 0>(hA, (const u32*)cA, hB, cB, nullptr, nullptr, nullptr,
                         Bfrag, WpA, WpU, &sIds[7], 0, 0, 8, lane15, quad, wv);
    __syncthreads();
    // L2: 4 valid, hB -> hA
    sweep_level<1, 0, 0>(hB, (const u32*)cB, hA, cA, nullptr, nullptr, nullptr,
                         Bfrag, WpA, WpU, &sIds[3], 0, 0, 4, lane15, quad, wv);
    __syncthreads();
    // L1: 2 valid, hA -> hB
    sweep_level<1, 0, 0>(hA, (const u32*)cA, hB, cB, nullptr, nullptr, nullptr,
                         Bfrag, WpA, WpU, &sIds[1], 0, 0, 2, lane15, quad, wv);
    __syncthreads();
    // L0 -> fp32 hroot
    sweep_level<1, 2, 0>(hB, (const u32*)cB, nullptr, nullptr, nullptr, nullptr,
                         hroot, Bfrag, WpA, WpU, &sIds[0], 0, 0, 1, lane15, quad, wv);
    __syncthreads();

    // ---- head: wave 0 only
    if (wv == 0) {
        float a = b1[lane];
        #pragma unroll 8
        for (int k = 0; k < 64; ++k) a += hroot[k] * W1[k * 64 + lane];
        float r1 = fmaxf(a, 0.f);
        float f = b2[lane];
        #pragma unroll 8
        for (int k = 0; k < 64; ++k) f += __shfl(r1, k) * W2[k * 64 + lane];
        float gi = b_lstm[lane], gg = b_lstm[128 + lane], go = b_lstm[192 + lane];
        #pragma unroll 8
        for (int k = 0; k < 64; ++k) {
            float fk = __shfl(f, k);
            gi += fk * W_ih[k * 256 + lane];
            gg += fk * W_ih[k * 256 + 128 + lane];
            go += fk * W_ih[k * 256 + 192 + lane];
        }
        float cg = fsig(gi) * ftanh(gg);
        float hg = fsig(go) * ftanh(cg);
        int tt = (lane < 20) ? lane : 19;
        float dot = 0.f;
        #pragma unroll 8
        for (int k = 0; k < 64; ++k) {
            float fk = __shfl(f, k), hk = __shfl(hg, k);
            dot += fk * actor_W[k * 20 + tt] + hk * actor_W[(64 + k) * 20 + tt];
        }
        float m = vm[tt];
        float lg = logf(m) + dot * m + actor_b[tt] * m;
        float mx = -1e30f;
        #pragma unroll
        for (int j = 0; j < 20; ++j) mx = fmaxf(mx, __shfl(lg, j));
        float s = 0.f;
        #pragma unroll
        for (int j = 0; j < 20; ++j) s += __expf((__shfl(lg, j) - mx) * (1.0f / 3.0f));
        if (lane < 20) out[b * 20 + lane] = __expf((lg - mx) * (1.0f / 3.0f)) / s;
    }
}

// ---------------------------------------------------------------------------
extern "C" void kernel_launch(void* const* d_in, const int* in_sizes, int n_in,
                              void* d_out, int out_size, void* d_ws, size_t ws_size,
                              hipStream_t stream)
{
    const int*   x_idx   = (const int*)d_in[0];
    const float* vm      = (const float*)d_in[1];
    const float* Wx      = (const float*)d_in[2];
    const float* Ua      = (const float*)d_in[3];
    const float* Ub      = (const float*)d_in[4];
    const float* b_tree  = (const float*)d_in[5];
    const float* W_ih    = (const float*)d_in[6];
    const float* b_lstm  = (const float*)d_in[8];
    const float* W1      = (const float*)d_in[9];
    const float* b1      = (const float*)d_in[10];
    const float* W2      = (const float*)d_in[11];
    const float* b2      = (const float*)d_in[12];
    const float* actor_W = (const float*)d_in[13];
    const float* actor_b = (const float*)d_in[14];
    float* out = (float*)d_out;

    char* ws = (char*)d_ws;
    float4* WpA  = (float4*)ws;  ws += 128 * 64 * 16;
    float4* TaA  = (float4*)ws;  ws += 128 * 64 * 16;
    float4* TbA  = (float4*)ws;  ws += 128 * 64 * 16;
    float2* TaUC = (float2*)ws;  ws += 128 * 64 * 8;
    float2* TbUC = (float2*)ws;  ws += 128 * 64 * 8;
    float*  WpU  = (float*)ws;   ws += 128 * 64 * 4;
    u16*    h7   = (u16*)ws;     ws += 128 * 8192 * 2;
    u16*    c7   = (u16*)ws;     ws += 128 * 8192 * 2;
    u16*    Uswz = (u16*)ws;     ws += 128 * 320 * 2;

    precompute_kernel<<<128, 320, 0, stream>>>(Wx, b_tree, Ua, Ub,
                                               WpA, WpU, TaA, TaUC, TbA, TbUC, Uswz);
    sweepA_kernel<<<2048, 256, 0, stream>>>(x_idx, WpA, WpU, TaA, TaUC,
                                            TbA, TbUC, Uswz, h7, c7);
    sweepB_kernel<<<128, 256, 0, stream>>>(x_idx, WpA, WpU, Uswz, h7, c7,
                                           W1, b1, W2, b2, W_ih, b_lstm,
                                           actor_W, actor_b, vm, out);
}

// Round 8
// 182.954 us; speedup vs baseline: 1.9816x; 1.3898x over previous
//
#include <hip/hip_runtime.h>

// ---------------------------------------------------------------------------
// SympleAgent Tree-LSTM on MI355X — R8: R7 structure with the spill fixed.
// __launch_bounds__(256,2) on sweepA (R7's (256,5) forced ~100 VGPRs of
// scratch spill -> 400 MB of traffic/dispatch). LDS 27.9 KB keeps ~5
// blocks/CU; ids staged in LDS; 6-exp+3-rcp gate math; sweepB reads L7
// state straight from global.
// ---------------------------------------------------------------------------

typedef unsigned short u16;
typedef unsigned int   u32;
typedef __attribute__((ext_vector_type(8))) short  short8;   // 8 bf16
typedef __attribute__((ext_vector_type(4))) float  floatx4;  // MFMA C/D frag

__device__ __forceinline__ float frcp(float x) { return __fdividef(1.0f, x); }
__device__ __forceinline__ float fsig(float x) { return frcp(1.0f + __expf(-x)); }
__device__ __forceinline__ float ftanh(float x) {
    return 1.0f - 2.0f * frcp(__expf(2.0f * x) + 1.0f);
}
__device__ __forceinline__ u16 f2bfa(float x) {  // round-to-nearest
    return (u16)((__float_as_uint(x) + 0x8000u) >> 16);
}
__device__ __forceinline__ float bflo(u32 cc) { return __uint_as_float(cc << 16); }
__device__ __forceinline__ float bfhi(u32 cc) { return __uint_as_float(cc & 0xFFFF0000u); }

// Full LSTM gate evaluation with shared reciprocals: 6 exp + 3 rcp.
// -40 clamps keep every overflow path at its correct limit.
__device__ __forceinline__ void lstm_gates(
    float zi, float zfa, float zfb, float zo, float zu,
    float ca, float cb, float& c, float& h)
{
    zi  = fmaxf(zi, -40.f);  zfa = fmaxf(zfa, -40.f);
    zfb = fmaxf(zfb, -40.f); zo  = fmaxf(zo, -40.f);
    zu  = fmaxf(zu, -40.f);
    float ei  = __expf(-zi),  efa = __expf(-zfa);
    float efb = __expf(-zfb), eo  = __expf(-zo);
    float eu2 = __expf(-2.f * zu);
    float pfa = 1.f + efa, pfb = 1.f + efb;
    float cf = (ca * pfb + cb * pfa) * frcp(pfa * pfb);
    c = (1.f - eu2) * frcp((1.f + ei) * (1.f + eu2)) + cf;
    float cc = fmaxf(c, -40.f);
    float ec2 = __expf(-2.f * cc);
    h = (1.f - ec2) * frcp((1.f + eo) * (1.f + ec2));
}

#define HS 76   // h LDS row stride (u16): ~2-way bank aliasing only (free)

// ---------------- precompute: dense fp32 tables + swizzled bf16 U ----------
// grid 128 (block per vocab id), block 320.
// WpA [id][hh] float4 = (i,fa,fb,o) of Wx[id]+b; WpU float = u gate.
// TaA/TaUC: leaf_h[id]@Ua, UC=(u, leaf_c); TbA/TbUC with Ub.
// Uswz: B-frag order, elem ((kc*20+nt)*64+lane)*8+j =
//       U[kc*32+(lane>>4)*8+j][nt*16+(lane&15)], U = vstack(Ua,Ub) (128x320).
__global__ void precompute_kernel(
    const float* __restrict__ Wx, const float* __restrict__ b_tree,
    const float* __restrict__ Ua, const float* __restrict__ Ub,
    float4* __restrict__ WpA, float* __restrict__ WpU,
    float4* __restrict__ TaA, float2* __restrict__ TaUC,
    float4* __restrict__ TbA, float2* __restrict__ TbUC,
    u16* __restrict__ Uswz)
{
    int v = blockIdx.x;
    int t = threadIdx.x;
    __shared__ float sz[320], sta[320], stb[320], sh[64], sc[64];
    float z = Wx[v * 320 + t] + b_tree[t];
    sz[t] = z;
    {   // Uswz: one element per thread (128*320 total)
        int f = v * 320 + t;
        int j = f & 7, lane = (f >> 3) & 63, tk = f >> 9;
        int nt = tk % 20, kc = tk / 20;
        int k = kc * 32 + (lane >> 4) * 8 + j;
        int nn = nt * 16 + (lane & 15);
        float uval = (k < 64) ? Ua[k * 320 + nn] : Ub[(k - 64) * 320 + nn];
        Uswz[f] = (u16)((__float_as_uint(uval) + 0x7FFFu +
                         ((__float_as_uint(uval) >> 16) & 1u)) >> 16);
    }
    __syncthreads();
    if (t < 64) {
        float c = fsig(sz[t]) * ftanh(sz[256 + t]);
        float h = fsig(sz[192 + t]) * ftanh(c);
        sc[t] = c; sh[t] = h;
    }
    __syncthreads();
    float ta = 0.f, tb = 0.f;
    #pragma unroll 8
    for (int k = 0; k < 64; ++k) {
        ta += sh[k] * Ua[k * 320 + t];
        tb += sh[k] * Ub[k * 320 + t];
    }
    sta[t] = ta; stb[t] = tb;
    __syncthreads();
    if (t < 64) {
        int o = (v << 6) + t;
        WpA[o]  = make_float4(sz[t],  sz[64 + t],  sz[128 + t],  sz[192 + t]);
        WpU[o]  = sz[256 + t];
        TaA[o]  = make_float4(sta[t], sta[64 + t], sta[128 + t], sta[192 + t]);
        TaUC[o] = make_float2(sta[256 + t], sc[t]);
        TbA[o]  = make_float4(stb[t], stb[64 + t], stb[128 + t], stb[192 + t]);
        TbUC[o] = make_float2(stb[256 + t], sc[t]);
    }
}

// ---------------- one level call: NT 16-row tiles, MFMA + gate epilogue ----
// Wave wv owns hidden cols [wv*16,wv*16+16) for all 5 gates; every wave
// processes every tile. GSRC=1: A/c from global (h row stride 64 u16, c
// paired u32); GSRC=0: LDS (stride HS / paired u32).
// MODE 0: LDS dst; MODE 1: global dst (guarded by nvalid); MODE 2: hroot.
template<int NT, int MODE, int GSRC>
__device__ __forceinline__ void sweep_level(
    const u16* hsrc, const u32* csrc,
    u16* hdst, u16* cdst, u16* hg, u16* cg, float* hroot,
    const short8 Bfrag[4][5],
    const float4* __restrict__ WpA, const float* __restrict__ WpU,
    const int* ids, int lbase, int node0g, int nvalid,
    int lane15, int quad, int wv)
{
    floatx4 acc[NT][5];
    #pragma unroll
    for (int mt = 0; mt < NT; ++mt)
        #pragma unroll
        for (int g = 0; g < 5; ++g) acc[mt][g] = (floatx4){0.f, 0.f, 0.f, 0.f};

    #pragma unroll
    for (int mt = 0; mt < NT; ++mt) {
        #pragma unroll
        for (int kc = 0; kc < 4; ++kc) {
            int child = 2 * (lbase + mt * 16 + lane15) + (kc >> 1);
            const u16* ap = GSRC ? (hsrc + child * 64 + (kc & 1) * 32 + quad * 8)
                                 : (hsrc + child * HS + (kc & 1) * 32 + quad * 8);
            short8 a = *(const short8*)ap;
            #pragma unroll
            for (int g = 0; g < 5; ++g)
                acc[mt][g] = __builtin_amdgcn_mfma_f32_16x16x32_bf16(
                    a, Bfrag[kc][g], acc[mt][g], 0, 0, 0);
        }
    }
    int hh = wv * 16 + lane15;
    #pragma unroll
    for (int mt = 0; mt < NT; ++mt) {
        #pragma unroll
        for (int r = 0; r < 4; ++r) {
            int lrow = lbase + mt * 16 + quad * 4 + r;
            int id = ids[lrow];
            float4 wg = WpA[(id << 6) + hh];
            float  wu = WpU[(id << 6) + hh];
            u32 cc = csrc[lrow * 64 + hh];   // children c pair of parent lrow
            float c, h;
            lstm_gates(acc[mt][0][r] + wg.x, acc[mt][1][r] + wg.y,
                       acc[mt][2][r] + wg.z, acc[mt][3][r] + wg.w,
                       acc[mt][4][r] + wu, bflo(cc), bfhi(cc), c, h);
            if (MODE == 0) {
                hdst[lrow * HS + hh] = f2bfa(h);
                cdst[(lrow >> 1) * 128 + hh * 2 + (lrow & 1)] = f2bfa(c);
            }
            if (MODE == 1) {
                if (lrow < nvalid) {
                    int node = node0g + lrow;
                    hg[node * 64 + hh] = f2bfa(h);
                    cg[(node >> 1) * 128 + hh * 2 + (node & 1)] = f2bfa(c);
                }
            }
            if (MODE == 2) {
                if (lrow == 0) hroot[hh] = h;
            }
        }
    }
}

__device__ __forceinline__ void load_bfrags(short8 Bfrag[4][5],
                                            const u16* __restrict__ Uswz,
                                            int wv, int lane)
{
    #pragma unroll
    for (int kc = 0; kc < 4; ++kc)
        #pragma unroll
        for (int g = 0; g < 5; ++g) {
            int nt = g * 4 + wv;
            Bfrag[kc][g] = *(const short8*)(Uswz + ((kc * 20 + nt) * 64 + lane) * 8);
        }
}

// ---------------- phase A: L10..L7, grid 2048 = 128 x 16 subtrees ----------
// LDS 27904 B (5 blocks/CU LDS-wise); bounds(256,2) -> no VGPR spill.
__global__ __launch_bounds__(256, 2) void sweepA_kernel(
    const int* __restrict__ x_idx,
    const float4* __restrict__ WpA, const float* __restrict__ WpU,
    const float4* __restrict__ TaA, const float2* __restrict__ TaUC,
    const float4* __restrict__ TbA, const float2* __restrict__ TbUC,
    const u16* __restrict__ Uswz,
    u16* __restrict__ h7, u16* __restrict__ c7)
{
    __shared__ u16 hA[64 * HS];
    __shared__ u16 cA[32 * 128];     // paired bf16: [pair][hh][parity]
    __shared__ u16 hB[32 * HS];
    __shared__ u16 cB[16 * 128];
    __shared__ int sIds[256];
    int t = threadIdx.x, lane = t & 63, wv = t >> 6;
    int lane15 = lane & 15, quad = lane >> 4;
    int b = blockIdx.x >> 4, st = blockIdx.x & 15;
    const int* xb = x_idx + b * 4095;
    u16* h7b = h7 + (size_t)b * 8192;
    u16* c7b = c7 + (size_t)b * 8192;

    // ---- stage this subtree's ids (coalesced)
    if      (t < 64)  sIds[t] = xb[1023 + st * 64 + t];           // L10
    else if (t < 192) sIds[t] = xb[2047 + st * 128 + (t - 64)];   // leaves
    else if (t < 224) sIds[t] = xb[511 + st * 32 + (t - 192)];    // L9
    else if (t < 240) sIds[t] = xb[255 + st * 16 + (t - 224)];    // L8
    else if (t < 248) sIds[t] = xb[127 + st * 8 + (t - 240)];     // L7
    else              sIds[t] = 0;
    __syncthreads();

    // ---- L10: 16 rows per wave, lane = hidden col, ids from LDS
    #pragma unroll 4
    for (int rr = 0; rr < 16; ++rr) {
        int rl = wv * 16 + rr;
        int id = sIds[rl], ida = sIds[64 + 2 * rl], idb = sIds[65 + 2 * rl];
        float4 wg = WpA[(id << 6) + lane];   float  wu = WpU[(id << 6) + lane];
        float4 ga = TaA[(ida << 6) + lane];  float2 ua = TaUC[(ida << 6) + lane];
        float4 gb = TbA[(idb << 6) + lane];  float2 ub = TbUC[(idb << 6) + lane];
        float c, h;
        lstm_gates(wg.x + ga.x + gb.x, wg.y + ga.y + gb.y, wg.z + ga.z + gb.z,
                   wg.w + ga.w + gb.w, wu + ua.x + ub.x, ua.y, ub.y, c, h);
        hA[rl * HS + lane] = f2bfa(h);
        cA[(rl >> 1) * 128 + lane * 2 + (rl & 1)] = f2bfa(c);
    }
    short8 Bfrag[4][5];
    load_bfrags(Bfrag, Uswz, wv, lane);
    __syncthreads();
    // ---- L9: 32 rows (2 tiles), hA/cA -> hB/cB
    sweep_level<2, 0, 0>(hA, (const u32*)cA, hB, cB, nullptr, nullptr, nullptr,
                         Bfrag, WpA, WpU, &sIds[192], 0, 0, 32, lane15, quad, wv);
    __syncthreads();
    // ---- L8: 16 rows (1 tile), hB/cB -> hA/cA
    sweep_level<1, 0, 0>(hB, (const u32*)cB, hA, cA, nullptr, nullptr, nullptr,
                         Bfrag, WpA, WpU, &sIds[224], 0, 0, 16, lane15, quad, wv);
    __syncthreads();
    // ---- L7: 8 valid rows of 1 tile, hA/cA -> global slice [st*8, st*8+8)
    sweep_level<1, 1, 0>(hA, (const u32*)cA, nullptr, nullptr, h7b, c7b, nullptr,
                         Bfrag, WpA, WpU, &sIds[240], 0, st * 8, 8, lane15, quad, wv);
}

// ---------------- phase B: L6..L0 + head, grid 128 -------------------------
__global__ __launch_bounds__(256, 2) void sweepB_kernel(
    const int* __restrict__ x_idx,
    const float4* __restrict__ WpA, const float* __restrict__ WpU,
    const u16* __restrict__ Uswz,
    const u16* __restrict__ h7, const u16* __restrict__ c7,
    const float* __restrict__ W1, const float* __restrict__ b1,
    const float* __restrict__ W2, const float* __restrict__ b2,
    const float* __restrict__ W_ih, const float* __restrict__ b_lstm,
    const float* __restrict__ actor_W, const float* __restrict__ actor_b,
    const float* __restrict__ vm, float* __restrict__ out)
{
    __shared__ u16 hA[64 * HS];
    __shared__ u16 cA[32 * 128];
    __shared__ u16 hB[32 * HS];
    __shared__ u16 cB[16 * 128];
    __shared__ int sIds[128];
    __shared__ float hroot[64];
    int t = threadIdx.x, lane = t & 63, wv = t >> 6;
    int lane15 = lane & 15, quad = lane >> 4;
    int b = blockIdx.x;
    const int* xb = x_idx + b * 4095;
    const u16* h7b = h7 + (size_t)b * 8192;
    const u16* c7b = c7 + (size_t)b * 8192;

    if (t < 127) sIds[t] = xb[t];   // level L's ids start at sIds[(1<<L)-1]
    short8 Bfrag[4][5];
    load_bfrags(Bfrag, Uswz, wv, lane);
    __syncthreads();
    // L6: 64 rows (2x NT=2 tiles) straight from global h7/c7 -> hA/cA
    sweep_level<2, 0, 1>(h7b, (const u32*)c7b, hA, cA, nullptr, nullptr, nullptr,
                         Bfrag, WpA, WpU, &sIds[63], 0, 0, 64, lane15, quad, wv);
    sweep_level<2, 0, 1>(h7b, (const u32*)c7b, hA, cA, nullptr, nullptr, nullptr,
                         Bfrag, WpA, WpU, &sIds[63], 32, 0, 64, lane15, quad, wv);
    __syncthreads();
    // L5: 32 rows, hA -> hB
    sweep_level<2, 0, 0>(hA, (const u32*)cA, hB, cB, nullptr, nullptr, nullptr,
                         Bfrag, WpA, WpU, &sIds[31], 0, 0, 32, lane15, quad, wv);
    __syncthreads();
    // L4: 16 rows, hB -> hA
    sweep_level<1, 0, 0>(hB, (const u32*)cB, hA, cA, nullptr, nullptr, nullptr,
                         Bfrag, WpA, WpU, &sIds[15], 0, 0, 16, lane15, quad, wv);
    __syncthreads();
    // L3: 8 valid, hA -> hB (garbage rows bounded, in-bounds)
    sweep_level<1, 0, 0>(hA, (const u32*)cA, hB, cB, nullptr, nullptr, nullptr,
                         Bfrag, WpA, WpU, &sIds[7], 0, 0, 8, lane15, quad, wv);
    __syncthreads();
    // L2: 4 valid, hB -> hA
    sweep_level<1, 0, 0>(hB, (const u32*)cB, hA, cA, nullptr, nullptr, nullptr,
                         Bfrag, WpA, WpU, &sIds[3], 0, 0, 4, lane15, quad, wv);
    __syncthreads();
    // L1: 2 valid, hA -> hB
    sweep_level<1, 0, 0>(hA, (const u32*)cA, hB, cB, nullptr, nullptr, nullptr,
                         Bfrag, WpA, WpU, &sIds[1], 0, 0, 2, lane15, quad, wv);
    __syncthreads();
    // L0 -> fp32 hroot
    sweep_level<1, 2, 0>(hB, (const u32*)cB, nullptr, nullptr, nullptr, nullptr,
                         hroot, Bfrag, WpA, WpU, &sIds[0], 0, 0, 1, lane15, quad, wv);
    __syncthreads();

    // ---- head: wave 0 only
    if (wv == 0) {
        float a = b1[lane];
        #pragma unroll 8
        for (int k = 0; k < 64; ++k) a += hroot[k] * W1[k * 64 + lane];
        float r1 = fmaxf(a, 0.f);
        float f = b2[lane];
        #pragma unroll 8
        for (int k = 0; k < 64; ++k) f += __shfl(r1, k) * W2[k * 64 + lane];
        float gi = b_lstm[lane], gg = b_lstm[128 + lane], go = b_lstm[192 + lane];
        #pragma unroll 8
        for (int k = 0; k < 64; ++k) {
            float fk = __shfl(f, k);
            gi += fk * W_ih[k * 256 + lane];
            gg += fk * W_ih[k * 256 + 128 + lane];
            go += fk * W_ih[k * 256 + 192 + lane];
        }
        float cg = fsig(gi) * ftanh(gg);
        float hg = fsig(go) * ftanh(cg);
        int tt = (lane < 20) ? lane : 19;
        float dot = 0.f;
        #pragma unroll 8
        for (int k = 0; k < 64; ++k) {
            float fk = __shfl(f, k), hk = __shfl(hg, k);
            dot += fk * actor_W[k * 20 + tt] + hk * actor_W[(64 + k) * 20 + tt];
        }
        float m = vm[tt];
        float lg = logf(m) + dot * m + actor_b[tt] * m;
        float mx = -1e30f;
        #pragma unroll
        for (int j = 0; j < 20; ++j) mx = fmaxf(mx, __shfl(lg, j));
        float s = 0.f;
        #pragma unroll
        for (int j = 0; j < 20; ++j) s += __expf((__shfl(lg, j) - mx) * (1.0f / 3.0f));
        if (lane < 20) out[b * 20 + lane] = __expf((lg - mx) * (1.0f / 3.0f)) / s;
    }
}

// ---------------------------------------------------------------------------
extern "C" void kernel_launch(void* const* d_in, const int* in_sizes, int n_in,
                              void* d_out, int out_size, void* d_ws, size_t ws_size,
                              hipStream_t stream)
{
    const int*   x_idx   = (const int*)d_in[0];
    const float* vm      = (const float*)d_in[1];
    const float* Wx      = (const float*)d_in[2];
    const float* Ua      = (const float*)d_in[3];
    const float* Ub      = (const float*)d_in[4];
    const float* b_tree  = (const float*)d_in[5];
    const float* W_ih    = (const float*)d_in[6];
    const float* b_lstm  = (const float*)d_in[8];
    const float* W1      = (const float*)d_in[9];
    const float* b1      = (const float*)d_in[10];
    const float* W2      = (const float*)d_in[11];
    const float* b2      = (const float*)d_in[12];
    const float* actor_W = (const float*)d_in[13];
    const float* actor_b = (const float*)d_in[14];
    float* out = (float*)d_out;

    char* ws = (char*)d_ws;
    float4* WpA  = (float4*)ws;  ws += 128 * 64 * 16;
    float4* TaA  = (float4*)ws;  ws += 128 * 64 * 16;
    float4* TbA  = (float4*)ws;  ws += 128 * 64 * 16;
    float2* TaUC = (float2*)ws;  ws += 128 * 64 * 8;
    float2* TbUC = (float2*)ws;  ws += 128 * 64 * 8;
    float*  WpU  = (float*)ws;   ws += 128 * 64 * 4;
    u16*    h7   = (u16*)ws;     ws += 128 * 8192 * 2;
    u16*    c7   = (u16*)ws;     ws += 128 * 8192 * 2;
    u16*    Uswz = (u16*)ws;     ws += 128 * 320 * 2;

    precompute_kernel<<<128, 320, 0, stream>>>(Wx, b_tree, Ua, Ub,
                                               WpA, WpU, TaA, TaUC, TbA, TbUC, Uswz);
    sweepA_kernel<<<2048, 256, 0, stream>>>(x_idx, WpA, WpU, TaA, TaUC,
                                            TbA, TbUC, Uswz, h7, c7);
    sweepB_kernel<<<128, 256, 0, stream>>>(x_idx, WpA, WpU, Uswz, h7, c7,
                                           W1, b1, W2, b2, W_ih, b_lstm,
                                           actor_W, actor_b, vm, out);
}

// Round 9
// 150.264 us; speedup vs baseline: 2.4127x; 1.2176x over previous
//
#include <hip/hip_runtime.h>

// ---------------------------------------------------------------------------
// SympleAgent Tree-LSTM on MI355X — R9: deep sweepA (L10..L3), tiny sweepB.
// Budget analysis (R6 vs R3/R5/R8) shows the old grid-128 sweepB cost
// ~55-60 us (7 serial latency-exposed levels). Move L6..L3 into sweepA as
// garbage-padded tiles (throughput across 1024 blocks); sweepB = L2..L0+head.
// Gate math: tables & U pre-scaled by log2e (u by 2log2e) -> raw v_exp_f32.
// ---------------------------------------------------------------------------

typedef unsigned short u16;
typedef unsigned int   u32;
typedef __attribute__((ext_vector_type(8))) short  short8;   // 8 bf16
typedef __attribute__((ext_vector_type(4))) float  floatx4;  // MFMA C/D frag

#define L2E  1.44269504f
#define L2E2 2.885390082f

__device__ __forceinline__ float frcp(float x) { return __fdividef(1.0f, x); }
__device__ __forceinline__ float fsig(float x) { return frcp(1.0f + __expf(-x)); }
__device__ __forceinline__ float ftanh(float x) {
    return 1.0f - 2.0f * frcp(__expf(2.0f * x) + 1.0f);
}
__device__ __forceinline__ u16 f2bfa(float x) {  // round-to-nearest
    return (u16)((__float_as_uint(x) + 0x8000u) >> 16);
}
__device__ __forceinline__ float bflo(u32 cc) { return __uint_as_float(cc << 16); }
__device__ __forceinline__ float bfhi(u32 cc) { return __uint_as_float(cc & 0xFFFF0000u); }

// LSTM gates on log2e-PRESCALED pre-activations (zu by 2log2e): 6 raw
// v_exp_f32 + 3 v_rcp_f32. Clamps keep garbage/overflow at correct limits;
// fminf on the ec2 arg also stops NaN propagation from garbage rows.
__device__ __forceinline__ void lstm_gates(
    float zi, float zfa, float zfb, float zo, float zu,
    float ca, float cb, float& c, float& h)
{
    zi  = fmaxf(zi, -60.f);  zfa = fmaxf(zfa, -60.f);
    zfb = fmaxf(zfb, -60.f); zo  = fmaxf(zo, -60.f);
    zu  = fmaxf(zu, -60.f);
    float ei  = __builtin_amdgcn_exp2f(-zi);
    float efa = __builtin_amdgcn_exp2f(-zfa);
    float efb = __builtin_amdgcn_exp2f(-zfb);
    float eo  = __builtin_amdgcn_exp2f(-zo);
    float eu2 = __builtin_amdgcn_exp2f(-zu);
    float pfa = 1.f + efa, pfb = 1.f + efb;
    float cf = (ca * pfb + cb * pfa) * __builtin_amdgcn_rcpf(pfa * pfb);
    c = (1.f - eu2) * __builtin_amdgcn_rcpf((1.f + ei) * (1.f + eu2)) + cf;
    float ec2 = __builtin_amdgcn_exp2f(fminf(-c * L2E2, 80.f));
    h = (1.f - ec2) * __builtin_amdgcn_rcpf((1.f + eo) * (1.f + ec2));
}

#define HS 72   // h LDS row stride (u16): 144 B = 16B-aligned, 2-way banks

// ---------------- precompute: scaled fp32 tables + scaled bf16 U -----------
// WpA [id][hh] float4 = (i,fa,fb,o)*log2e of Wx[id]+b; WpU = u*2log2e.
// TaA/TaUC: leaf_h[id]@Ua scaled likewise, UC=(u*2log2e, leaf_c UNSCALED).
// Uswz: B-frag order, gate cols i,fa,fb,o scaled log2e; u cols 2log2e.
__global__ void precompute_kernel(
    const float* __restrict__ Wx, const float* __restrict__ b_tree,
    const float* __restrict__ Ua, const float* __restrict__ Ub,
    float4* __restrict__ WpA, float* __restrict__ WpU,
    float4* __restrict__ TaA, float2* __restrict__ TaUC,
    float4* __restrict__ TbA, float2* __restrict__ TbUC,
    u16* __restrict__ Uswz)
{
    int v = blockIdx.x;
    int t = threadIdx.x;
    __shared__ float sz[320], sta[320], stb[320], sh[64], sc[64];
    float z = Wx[v * 320 + t] + b_tree[t];
    sz[t] = z;
    {   // Uswz: one element per thread (128*320 total)
        int f = v * 320 + t;
        int j = f & 7, lane = (f >> 3) & 63, tk = f >> 9;
        int nt = tk % 20, kc = tk / 20;
        int k = kc * 32 + (lane >> 4) * 8 + j;
        int nn = nt * 16 + (lane & 15);
        float uval = (k < 64) ? Ua[k * 320 + nn] : Ub[(k - 64) * 320 + nn];
        uval *= ((nn >> 6) == 4) ? L2E2 : L2E;
        Uswz[f] = (u16)((__float_as_uint(uval) + 0x7FFFu +
                         ((__float_as_uint(uval) >> 16) & 1u)) >> 16);
    }
    __syncthreads();
    if (t < 64) {
        float c = fsig(sz[t]) * ftanh(sz[256 + t]);
        float h = fsig(sz[192 + t]) * ftanh(c);
        sc[t] = c; sh[t] = h;
    }
    __syncthreads();
    float ta = 0.f, tb = 0.f;
    #pragma unroll 8
    for (int k = 0; k < 64; ++k) {
        ta += sh[k] * Ua[k * 320 + t];
        tb += sh[k] * Ub[k * 320 + t];
    }
    sta[t] = ta; stb[t] = tb;
    __syncthreads();
    if (t < 64) {
        int o = (v << 6) + t;
        WpA[o]  = make_float4(sz[t] * L2E, sz[64 + t] * L2E,
                              sz[128 + t] * L2E, sz[192 + t] * L2E);
        WpU[o]  = sz[256 + t] * L2E2;
        TaA[o]  = make_float4(sta[t] * L2E, sta[64 + t] * L2E,
                              sta[128 + t] * L2E, sta[192 + t] * L2E);
        TaUC[o] = make_float2(sta[256 + t] * L2E2, sc[t]);
        TbA[o]  = make_float4(stb[t] * L2E, stb[64 + t] * L2E,
                              stb[128 + t] * L2E, stb[192 + t] * L2E);
        TbUC[o] = make_float2(stb[256 + t] * L2E2, sc[t]);
    }
}

// ---------------- one level call: NT 16-row tiles, MFMA + gate epilogue ----
// Wave wv owns hidden cols [wv*16,wv*16+16) for all 5 gates; every wave
// processes every tile. GSRC=1: A/c from global (h stride 64 u16, c paired).
// MODE 0: LDS dst; MODE 1: global dst (guarded by nvalid); MODE 2: hroot.
template<int NT, int MODE, int GSRC>
__device__ __forceinline__ void sweep_level(
    const u16* hsrc, const u32* csrc,
    u16* hdst, u16* cdst, u16* hg, u16* cg, float* hroot,
    const short8 Bfrag[4][5],
    const float4* __restrict__ WpA, const float* __restrict__ WpU,
    const int* ids, int lbase, int node0g, int nvalid,
    int lane15, int quad, int wv)
{
    floatx4 acc[NT][5];
    #pragma unroll
    for (int mt = 0; mt < NT; ++mt)
        #pragma unroll
        for (int g = 0; g < 5; ++g) acc[mt][g] = (floatx4){0.f, 0.f, 0.f, 0.f};

    #pragma unroll
    for (int mt = 0; mt < NT; ++mt) {
        #pragma unroll
        for (int kc = 0; kc < 4; ++kc) {
            int child = 2 * (lbase + mt * 16 + lane15) + (kc >> 1);
            const u16* ap = GSRC ? (hsrc + child * 64 + (kc & 1) * 32 + quad * 8)
                                 : (hsrc + child * HS + (kc & 1) * 32 + quad * 8);
            short8 a = *(const short8*)ap;
            #pragma unroll
            for (int g = 0; g < 5; ++g)
                acc[mt][g] = __builtin_amdgcn_mfma_f32_16x16x32_bf16(
                    a, Bfrag[kc][g], acc[mt][g], 0, 0, 0);
        }
    }
    int hh = wv * 16 + lane15;
    #pragma unroll
    for (int mt = 0; mt < NT; ++mt) {
        #pragma unroll
        for (int r = 0; r < 4; ++r) {
            int lrow = lbase + mt * 16 + quad * 4 + r;
            int id = ids[lrow];
            float4 wg = WpA[(id << 6) + hh];
            float  wu = WpU[(id << 6) + hh];
            u32 cc = csrc[lrow * 64 + hh];   // children c pair of parent lrow
            float c, h;
            lstm_gates(acc[mt][0][r] + wg.x, acc[mt][1][r] + wg.y,
                       acc[mt][2][r] + wg.z, acc[mt][3][r] + wg.w,
                       acc[mt][4][r] + wu, bflo(cc), bfhi(cc), c, h);
            if (MODE == 0) {
                hdst[lrow * HS + hh] = f2bfa(h);
                cdst[(lrow >> 1) * 128 + hh * 2 + (lrow & 1)] = f2bfa(c);
            }
            if (MODE == 1) {
                if (lrow < nvalid) {
                    int node = node0g + lrow;
                    hg[node * 64 + hh] = f2bfa(h);
                    cg[(node >> 1) * 128 + hh * 2 + (node & 1)] = f2bfa(c);
                }
            }
            if (MODE == 2) {
                if (lrow == 0) hroot[hh] = h;
            }
        }
    }
}

__device__ __forceinline__ void load_bfrags(short8 Bfrag[4][5],
                                            const u16* __restrict__ Uswz,
                                            int wv, int lane)
{
    #pragma unroll
    for (int kc = 0; kc < 4; ++kc)
        #pragma unroll
        for (int g = 0; g < 5; ++g) {
            int nt = g * 4 + wv;
            Bfrag[kc][g] = *(const short8*)(Uswz + ((kc * 20 + nt) * 64 + lane) * 8);
        }
}

// ---------------- phase A: L10..L3, grid 1024 = 128 x 8 subtrees -----------
// 128 L10-rows per block; L10..L7 full tiles (zero waste); L6..L3 padded
// 16-row tiles (8/4/2/1 valid). Writes 1 L3 row per block. LDS ~54.4 KB.
__global__ __launch_bounds__(256, 2) void sweepA_kernel(
    const int* __restrict__ x_idx,
    const float4* __restrict__ WpA, const float* __restrict__ WpU,
    const float4* __restrict__ TaA, const float2* __restrict__ TaUC,
    const float4* __restrict__ TbA, const float2* __restrict__ TbUC,
    const u16* __restrict__ Uswz,
    u16* __restrict__ h3, u16* __restrict__ c3)
{
    __shared__ u16 hA[128 * HS];     // 18432 B
    __shared__ u16 cA[64 * 128];     // 16384 B (paired bf16)
    __shared__ u16 hB[64 * HS];      // 9216 B
    __shared__ u16 cB[32 * 128];     // 8192 B
    __shared__ int sIds[544];        // 511 ids + zero pad (garbage-id safety)
    int t = threadIdx.x, lane = t & 63, wv = t >> 6;
    int lane15 = lane & 15, quad = lane >> 4;
    int b = blockIdx.x >> 3, st = blockIdx.x & 7;
    const int* xb = x_idx + b * 4095;

    // ---- stage this subtree's ids (coalesced), zero-fill the pad
    for (int i = t; i < 544; i += 256) {
        int g;
        if      (i < 128) g = 1023 + st * 128 + i;              // L10
        else if (i < 384) g = 2047 + st * 256 + (i - 128);      // leaves
        else if (i < 448) g = 511 + st * 64 + (i - 384);        // L9
        else if (i < 480) g = 255 + st * 32 + (i - 448);        // L8
        else if (i < 496) g = 127 + st * 16 + (i - 480);        // L7
        else if (i < 504) g = 63 + st * 8 + (i - 496);          // L6
        else if (i < 508) g = 31 + st * 4 + (i - 504);          // L5
        else if (i < 510) g = 15 + st * 2 + (i - 508);          // L4
        else if (i == 510) g = 7 + st;                          // L3
        else g = -1;
        sIds[i] = (g >= 0) ? xb[g] : 0;
    }
    __syncthreads();

    // ---- L10: 32 rows per wave, lane = hidden col, ids from LDS
    #pragma unroll 4
    for (int rr = 0; rr < 32; ++rr) {
        int rl = wv * 32 + rr;
        int id = sIds[rl], ida = sIds[128 + 2 * rl], idb = sIds[129 + 2 * rl];
        float4 wg = WpA[(id << 6) + lane];   float  wu = WpU[(id << 6) + lane];
        float4 ga = TaA[(ida << 6) + lane];  float2 ua = TaUC[(ida << 6) + lane];
        float4 gb = TbA[(idb << 6) + lane];  float2 ub = TbUC[(idb << 6) + lane];
        float c, h;
        lstm_gates(wg.x + ga.x + gb.x, wg.y + ga.y + gb.y, wg.z + ga.z + gb.z,
                   wg.w + ga.w + gb.w, wu + ua.x + ub.x, ua.y, ub.y, c, h);
        hA[rl * HS + lane] = f2bfa(h);
        cA[(rl >> 1) * 128 + lane * 2 + (rl & 1)] = f2bfa(c);
    }
    short8 Bfrag[4][5];
    load_bfrags(Bfrag, Uswz, wv, lane);
    __syncthreads();
    // ---- L9: 64 rows (2x NT=2), hA/cA -> hB/cB
    sweep_level<2, 0, 0>(hA, (const u32*)cA, hB, cB, nullptr, nullptr, nullptr,
                         Bfrag, WpA, WpU, &sIds[384], 0, 0, 64, lane15, quad, wv);
    sweep_level<2, 0, 0>(hA, (const u32*)cA, hB, cB, nullptr, nullptr, nullptr,
                         Bfrag, WpA, WpU, &sIds[384], 32, 0, 64, lane15, quad, wv);
    __syncthreads();
    // ---- L8: 32 rows, hB/cB -> hA/cA
    sweep_level<2, 0, 0>(hB, (const u32*)cB, hA, cA, nullptr, nullptr, nullptr,
                         Bfrag, WpA, WpU, &sIds[448], 0, 0, 32, lane15, quad, wv);
    __syncthreads();
    // ---- L7: 16 rows, hA/cA -> hB/cB
    sweep_level<1, 0, 0>(hA, (const u32*)cA, hB, cB, nullptr, nullptr, nullptr,
                         Bfrag, WpA, WpU, &sIds[480], 0, 0, 16, lane15, quad, wv);
    __syncthreads();
    // ---- L6: 8 valid of 16, hB -> hA
    sweep_level<1, 0, 0>(hB, (const u32*)cB, hA, cA, nullptr, nullptr, nullptr,
                         Bfrag, WpA, WpU, &sIds[496], 0, 0, 8, lane15, quad, wv);
    __syncthreads();
    // ---- L5: 4 valid, hA -> hB
    sweep_level<1, 0, 0>(hA, (const u32*)cA, hB, cB, nullptr, nullptr, nullptr,
                         Bfrag, WpA, WpU, &sIds[504], 0, 0, 4, lane15, quad, wv);
    __syncthreads();
    // ---- L4: 2 valid, hB -> hA
    sweep_level<1, 0, 0>(hB, (const u32*)cB, hA, cA, nullptr, nullptr, nullptr,
                         Bfrag, WpA, WpU, &sIds[508], 0, 0, 2, lane15, quad, wv);
    __syncthreads();
    // ---- L3: 1 valid row -> global (batch-local node st)
    sweep_level<1, 1, 0>(hA, (const u32*)cA, nullptr, nullptr,
                         h3 + (size_t)b * 512, c3 + (size_t)b * 512, nullptr,
                         Bfrag, WpA, WpU, &sIds[510], 0, st, 1, lane15, quad, wv);
}

// ---------------- phase B: L2..L0 + head, grid 128 -------------------------
__global__ __launch_bounds__(256, 2) void sweepB_kernel(
    const int* __restrict__ x_idx,
    const float4* __restrict__ WpA, const float* __restrict__ WpU,
    const u16* __restrict__ Uswz,
    const u16* __restrict__ h3, const u16* __restrict__ c3,
    const float* __restrict__ W1, const float* __restrict__ b1,
    const float* __restrict__ W2, const float* __restrict__ b2,
    const float* __restrict__ W_ih, const float* __restrict__ b_lstm,
    const float* __restrict__ actor_W, const float* __restrict__ actor_b,
    const float* __restrict__ vm, float* __restrict__ out)
{
    __shared__ u16 hA[32 * HS];
    __shared__ u16 cA[16 * 128];
    __shared__ u16 hB[32 * HS];
    __shared__ u16 cB[16 * 128];
    __shared__ int sIds[32];
    __shared__ float hroot[64];
    int t = threadIdx.x, lane = t & 63, wv = t >> 6;
    int lane15 = lane & 15, quad = lane >> 4;
    int b = blockIdx.x;
    const int* xb = x_idx + b * 4095;
    const u16* h3b = h3 + (size_t)b * 512;
    const u16* c3b = c3 + (size_t)b * 512;

    if (t < 32) sIds[t] = (t < 31) ? xb[t] : 0;
    short8 Bfrag[4][5];
    load_bfrags(Bfrag, Uswz, wv, lane);
    __syncthreads();
    // L2: 4 valid of 16, children from global h3/c3 -> hB/cB
    sweep_level<1, 0, 1>(h3b, (const u32*)c3b, hB, cB, nullptr, nullptr, nullptr,
                         Bfrag, WpA, WpU, &sIds[3], 0, 0, 4, lane15, quad, wv);
    __syncthreads();
    // L1: 2 valid, hB -> hA
    sweep_level<1, 0, 0>(hB, (const u32*)cB, hA, cA, nullptr, nullptr, nullptr,
                         Bfrag, WpA, WpU, &sIds[1], 0, 0, 2, lane15, quad, wv);
    __syncthreads();
    // L0 -> fp32 hroot
    sweep_level<1, 2, 0>(hA, (const u32*)cA, nullptr, nullptr, nullptr, nullptr,
                         hroot, Bfrag, WpA, WpU, &sIds[0], 0, 0, 1, lane15, quad, wv);
    __syncthreads();

    // ---- head: wave 0 only
    if (wv == 0) {
        float a = b1[lane];
        #pragma unroll 8
        for (int k = 0; k < 64; ++k) a += hroot[k] * W1[k * 64 + lane];
        float r1 = fmaxf(a, 0.f);
        float f = b2[lane];
        #pragma unroll 8
        for (int k = 0; k < 64; ++k) f += __shfl(r1, k) * W2[k * 64 + lane];
        float gi = b_lstm[lane], gg = b_lstm[128 + lane], go = b_lstm[192 + lane];
        #pragma unroll 8
        for (int k = 0; k < 64; ++k) {
            float fk = __shfl(f, k);
            gi += fk * W_ih[k * 256 + lane];
            gg += fk * W_ih[k * 256 + 128 + lane];
            go += fk * W_ih[k * 256 + 192 + lane];
        }
        float cg = fsig(gi) * ftanh(gg);
        float hg = fsig(go) * ftanh(cg);
        int tt = (lane < 20) ? lane : 19;
        float dot = 0.f;
        #pragma unroll 8
        for (int k = 0; k < 64; ++k) {
            float fk = __shfl(f, k), hk = __shfl(hg, k);
            dot += fk * actor_W[k * 20 + tt] + hk * actor_W[(64 + k) * 20 + tt];
        }
        float m = vm[tt];
        float lg = logf(m) + dot * m + actor_b[tt] * m;
        float mx = -1e30f;
        #pragma unroll
        for (int j = 0; j < 20; ++j) mx = fmaxf(mx, __shfl(lg, j));
        float s = 0.f;
        #pragma unroll
        for (int j = 0; j < 20; ++j) s += __expf((__shfl(lg, j) - mx) * (1.0f / 3.0f));
        if (lane < 20) out[b * 20 + lane] = __expf((lg - mx) * (1.0f / 3.0f)) / s;
    }
}

// ---------------------------------------------------------------------------
extern "C" void kernel_launch(void* const* d_in, const int* in_sizes, int n_in,
                              void* d_out, int out_size, void* d_ws, size_t ws_size,
                              hipStream_t stream)
{
    const int*   x_idx   = (const int*)d_in[0];
    const float* vm      = (const float*)d_in[1];
    const float* Wx      = (const float*)d_in[2];
    const float* Ua      = (const float*)d_in[3];
    const float* Ub      = (const float*)d_in[4];
    const float* b_tree  = (const float*)d_in[5];
    const float* W_ih    = (const float*)d_in[6];
    const float* b_lstm  = (const float*)d_in[8];
    const float* W1      = (const float*)d_in[9];
    const float* b1      = (const float*)d_in[10];
    const float* W2      = (const float*)d_in[11];
    const float* b2      = (const float*)d_in[12];
    const float* actor_W = (const float*)d_in[13];
    const float* actor_b = (const float*)d_in[14];
    float* out = (float*)d_out;

    char* ws = (char*)d_ws;
    float4* WpA  = (float4*)ws;  ws += 128 * 64 * 16;
    float4* TaA  = (float4*)ws;  ws += 128 * 64 * 16;
    float4* TbA  = (float4*)ws;  ws += 128 * 64 * 16;
    float2* TaUC = (float2*)ws;  ws += 128 * 64 * 8;
    float2* TbUC = (float2*)ws;  ws += 128 * 64 * 8;
    float*  WpU  = (float*)ws;   ws += 128 * 64 * 4;
    u16*    h3   = (u16*)ws;     ws += 128 * 512 * 2;   // 8 L3 rows / batch
    u16*    c3   = (u16*)ws;     ws += 128 * 512 * 2;   // paired bf16
    u16*    Uswz = (u16*)ws;     ws += 128 * 320 * 2;

    precompute_kernel<<<128, 320, 0, stream>>>(Wx, b_tree, Ua, Ub,
                                               WpA, WpU, TaA, TaUC, TbA, TbUC, Uswz);
    sweepA_kernel<<<1024, 256, 0, stream>>>(x_idx, WpA, WpU, TaA, TaUC,
                                            TbA, TbUC, Uswz, h3, c3);
    sweepB_kernel<<<128, 256, 0, stream>>>(x_idx, WpA, WpU, Uswz, h3, c3,
                                           W1, b1, W2, b2, W_ih, b_lstm,
                                           actor_W, actor_b, vm, out);
}